// Round 6
// baseline (372.548 us; speedup 1.0000x reference)
//
#include <hip/hip_runtime.h>
#include <hip/hip_bf16.h>
#include <cfloat>
#include <math.h>

// ---------------- types ----------------
typedef __bf16 bf16x8 __attribute__((ext_vector_type(8)));
typedef float  f32x4  __attribute__((ext_vector_type(4)));

#define AMSM_MARGIN 0.35f
#define AMSM_SCALE  30.0f
#define AMSM_EPS    1e-12f

// ---------------- kernel 1/2: row-normalize f32 -> bf16 ----------------
__global__ __launch_bounds__(256) void rownorm_bf16(
    const float* __restrict__ src, __bf16* __restrict__ dst,
    int nrows, int nrows_pad)
{
    int row  = blockIdx.x * 4 + (threadIdx.x >> 6);
    int lane = threadIdx.x & 63;
    if (row >= nrows_pad) return;

    __bf16* drow = dst + (size_t)row * 512 + lane * 8;

    if (row >= nrows) {           // zero-fill pad rows (keeps MFMA garbage-free)
        bf16x8 z = {};
        *(bf16x8*)drow = z;
        return;
    }
    const float4* p = (const float4*)(src + (size_t)row * 512 + lane * 8);
    float4 a = p[0], b = p[1];
    float ss = a.x*a.x + a.y*a.y + a.z*a.z + a.w*a.w
             + b.x*b.x + b.y*b.y + b.z*b.z + b.w*b.w;
    #pragma unroll
    for (int m = 1; m < 64; m <<= 1) ss += __shfl_xor(ss, m, 64);
    float r = 1.0f / sqrtf(ss + AMSM_EPS);

    bf16x8 o;
    o[0] = (__bf16)(a.x*r); o[1] = (__bf16)(a.y*r);
    o[2] = (__bf16)(a.z*r); o[3] = (__bf16)(a.w*r);
    o[4] = (__bf16)(b.x*r); o[5] = (__bf16)(b.y*r);
    o[6] = (__bf16)(b.z*r); o[7] = (__bf16)(b.w*r);
    *(bf16x8*)drow = o;
}

// ---------------- kernel 3: 256x256 4-fat-phase fused GEMM + sum-exp ------
// BM=BN=256, BK=64, 8 waves (2M x 4N), per-wave C = 128x64.
// LDS: 8 regions of 16KB: region(b,ab,kh) = b*4 + ab*2 + kh, each [256][32] bf16.
// FAT phase = {12 ds_read_b128 + 2 half-tile stages + BAR + 32 MFMA + VMC(8) + BAR}
// (r5 had 16 MFMA per barrier-pair; 65 barriers/block -> 33 here).
// T2 swizzle: source k-chunk ^((q>>4)&2), read k ^((lo>>2)&2)  (conflicts = 0, r5).
#define NTILE  8      // 512 / 64
#define CTILES 391    // 100096 / 256

__device__ __forceinline__ void load_lds16(const void* g, void* l) {
    __builtin_amdgcn_global_load_lds(
        (const __attribute__((address_space(1))) void*)g,
        (__attribute__((address_space(3))) void*)l, 16, 0, 0);
}

#define BAR() __builtin_amdgcn_s_barrier()
#define VMC(N) asm volatile("s_waitcnt vmcnt(" #N ")" ::: "memory")

__global__ __launch_bounds__(512, 2) void amsm_gemm(
    const __bf16* __restrict__ xn, const __bf16* __restrict__ Wn,
    const int* __restrict__ lb,
    float* __restrict__ psum, float* __restrict__ tgt, int C, int CHUNKS)
{
    __shared__ __bf16 lds[8][8192];   // 128 KiB

    // T1: bijective XCD swizzle (3128 = 8 * 391, remainder 0)
    const int bid = blockIdx.x;
    const int wid = (bid & 7) * CTILES + (bid >> 3);
    const int mt  = wid & 7;            // m-tiles fast -> same-XCD blocks share W band
    const int ct  = wid >> 3;
    const int m0  = mt * 256;
    const int c0  = ct * 256;

    const int tid  = threadIdx.x;
    const int lane = tid & 63;
    const int w    = tid >> 6;
    const int wr   = w >> 2;            // 0..1 (M)
    const int wc   = w & 3;             // 0..3 (N)
    const int g    = lane >> 4;
    const int lo   = lane & 15;

    const __bf16* gA = xn + (size_t)m0 * 512;
    const __bf16* gB = Wn + (size_t)c0 * 512;

    // stage one 16KB half-tile (256 rows x 32 k) into region; pre-swizzled source
    auto stage = [&](int region, const __bf16* gbase) {
        #pragma unroll
        for (int iss = 0; iss < 2; ++iss) {
            const int q   = iss * 512 + tid;
            const int row = q >> 2;
            const int kc  = (q & 3) ^ ((q >> 4) & 2);   // T2 involution (source side)
            load_lds16(gbase + (size_t)row * 512 + kc * 8,
                       (char*)lds + region * 16384 + (iss * 512 + w * 64) * 16);
        }
    };

    const int kxb  = (g ^ ((lo >> 2) & 2)) * 16;        // T2 involution (read side), bytes
    const int aoff = (wr * 128 + lo) * 64 + kxb;        // byte offset within A region
    const int boff = (wc * 64  + lo) * 64 + kxb;        // within B region

    f32x4  acc[8][4] = {};
    bf16x8 af[8], bfr[4];

#define LDA(B, K) { const char* rb_ = (const char*)lds + ((B)*4 + (K))*16384 + aoff; \
    _Pragma("unroll") for (int mi_ = 0; mi_ < 8; ++mi_) \
        af[mi_] = *(const bf16x8*)(rb_ + mi_*1024); }
#define LDB4(B, K) { const char* rb_ = (const char*)lds + ((B)*4 + 2 + (K))*16384 + boff; \
    _Pragma("unroll") for (int ni_ = 0; ni_ < 4; ++ni_) \
        bfr[ni_] = *(const bf16x8*)(rb_ + ni_*1024); }
#define MM32() __builtin_amdgcn_s_setprio(1); \
    _Pragma("unroll") for (int mi_ = 0; mi_ < 8; ++mi_) \
      _Pragma("unroll") for (int ni_ = 0; ni_ < 4; ++ni_) \
        acc[mi_][ni_] = __builtin_amdgcn_mfma_f32_16x16x32_bf16(af[mi_], bfr[ni_], acc[mi_][ni_], 0,0,0); \
    __builtin_amdgcn_s_setprio(0);

    // ---- prologue: buf0 complete (t0), buf1.k0 (t1) ----
    stage(0, gA);            // buf0.A.k0
    stage(2, gB);            // buf0.B.k0
    stage(1, gA + 32);       // buf0.A.k1
    stage(3, gB + 32);       // buf0.B.k1
    stage(4, gA + 64);       // buf1.A.k0
    stage(6, gB + 64);       // buf1.B.k0
    VMC(4);                  // buf0 fully landed; buf1.k0 still in flight
    BAR();

    // steady-state audit (12 load instrs max outstanding; VMC(8) drains the
    // oldest 4 = exactly the regions the NEXT phase reads; every overwrite is
    // >=1 closing-barrier after its last read):
    #pragma unroll
    for (int it = 0; it < 3; ++it) {
        const size_t k1 = (size_t)(2 * it + 1) * 64;
        const size_t k2 = (size_t)(2 * it + 2) * 64;
        const size_t k3 = (size_t)(2 * it + 3) * 64;
        // ph0: read buf0.k0; stage buf1.{A,B}.k1 <- t+1
        LDA(0,0); LDB4(0,0);
        stage(5, gA + k1 + 32); stage(7, gB + k1 + 32);
        BAR(); MM32(); VMC(8); BAR();
        // ph1: read buf0.k1; stage buf0.{A,B}.k0 <- t+2
        LDA(0,1); LDB4(0,1);
        stage(0, gA + k2); stage(2, gB + k2);
        BAR(); MM32(); VMC(8); BAR();
        // ph2: read buf1.k0; stage buf0.{A,B}.k1 <- t+2
        LDA(1,0); LDB4(1,0);
        stage(1, gA + k2 + 32); stage(3, gB + k2 + 32);
        BAR(); MM32(); VMC(8); BAR();
        // ph3: read buf1.k1; stage buf1.{A,B}.k0 <- t+3
        LDA(1,1); LDB4(1,1);
        stage(4, gA + k3); stage(6, gB + k3);
        BAR(); MM32(); VMC(8); BAR();
    }
    // ---- tail iter (t0=6, t1=7; no t+2/t+3 stages; specialized VMCs) ----
    LDA(0,0); LDB4(0,0);
    stage(5, gA + (size_t)7 * 64 + 32); stage(7, gB + (size_t)7 * 64 + 32);
    BAR(); MM32(); VMC(8); BAR();      // drains r1,r3 (already needed-landed) / keeps 8
    LDA(0,1); LDB4(0,1);
    BAR(); MM32(); VMC(4); BAR();      // drains r4,r6 for ph2
    LDA(1,0); LDB4(1,0);
    BAR(); MM32(); VMC(0); BAR();      // drains r5,r7 for ph3
    LDA(1,1); LDB4(1,1);
    BAR(); MM32(); BAR();

    // ---- epilogue: C/D map col=lane&15 (class), row=(lane>>4)*4+reg (x-row) ----
    const int n_base = m0 + wr * 128;
    const int c_base = c0 + wc * 64;
    const int chunk  = ct * 4 + wc;

    #pragma unroll
    for (int mi = 0; mi < 8; ++mi) {
        #pragma unroll
        for (int j = 0; j < 4; ++j) {
            const int n = n_base + mi * 16 + g * 4 + j;
            const int target = lb[n];
            float s = 0.f;
            #pragma unroll
            for (int ni = 0; ni < 4; ++ni) {
                const int c = c_base + ni * 16 + lo;
                float logit = AMSM_SCALE * acc[mi][ni][j];
                if (c == target) {
                    logit -= AMSM_SCALE * AMSM_MARGIN;
                    tgt[n] = logit;                    // unique writer globally
                }
                // analytic bound: logit <= SCALE; exp(logit-SCALE) in [2.6e-31, 1]
                s += (c < C) ? __expf(logit - AMSM_SCALE) : 0.f;
            }
            #pragma unroll
            for (int m_ = 1; m_ < 16; m_ <<= 1) s += __shfl_xor(s, m_, 64);
            if (lo == 0) psum[(size_t)n * CHUNKS + chunk] = s;
        }
    }
#undef LDA
#undef LDB4
#undef MM32
}

// ---------------- kernel 4: per-row combine of partials ----------------
__global__ __launch_bounds__(256) void row_reduce(
    const float* __restrict__ psum, const float* __restrict__ tgt,
    float* __restrict__ row_loss, int CHUNKS)
{
    const int n = blockIdx.x;
    const int tid = threadIdx.x;
    __shared__ float sm[256];

    float s = 0.f;
    for (int j = tid; j < CHUNKS; j += 256) s += psum[(size_t)n * CHUNKS + j];
    sm[tid] = s; __syncthreads();
    for (int st = 128; st > 0; st >>= 1) {
        if (tid < st) sm[tid] += sm[tid + st];
        __syncthreads();
    }
    if (tid == 0) row_loss[n] = (logf(sm[0]) + AMSM_SCALE) - tgt[n];
}

// ---------------- kernel 5: mean over rows -> scalar ----------------
__global__ __launch_bounds__(256) void final_reduce(
    const float* __restrict__ row_loss, float* __restrict__ out, int N)
{
    const int tid = threadIdx.x;
    __shared__ float sm[256];
    float s = 0.f;
    for (int i = tid; i < N; i += 256) s += row_loss[i];
    sm[tid] = s; __syncthreads();
    for (int st = 128; st > 0; st >>= 1) {
        if (tid < st) sm[tid] += sm[tid + st];
        __syncthreads();
    }
    if (tid == 0) out[0] = sm[0] / (float)N;
}

// ---------------- launch ----------------
extern "C" void kernel_launch(void* const* d_in, const int* in_sizes, int n_in,
                              void* d_out, int out_size, void* d_ws, size_t ws_size,
                              hipStream_t stream) {
    const float* x  = (const float*)d_in[0];
    const float* W  = (const float*)d_in[1];
    const int*   lb = (const int*)d_in[2];
    float* out = (float*)d_out;

    constexpr int N  = 2048, D = 512, C = 100000;
    constexpr int C_PAD  = CTILES * 256;     // 100096
    constexpr int CHUNKS = CTILES * 4;       // 1564 (one per 64-col wave stripe)

    char* ws = (char*)d_ws;
    auto alloc = [&](size_t bytes) {
        char* p = ws; ws += (bytes + 255) & ~(size_t)255; return p;
    };
    __bf16* Wn   = (__bf16*)alloc((size_t)C_PAD * D * sizeof(__bf16)); // 102.5 MB
    __bf16* xn   = (__bf16*)alloc((size_t)N * D * sizeof(__bf16));     // 2 MB
    float*  psum = (float*)alloc((size_t)N * CHUNKS * sizeof(float));  // 12.8 MB
    float*  tgtv = (float*)alloc((size_t)N * sizeof(float));
    float*  rl   = (float*)alloc((size_t)N * sizeof(float));

    rownorm_bf16<<<N / 4, 256, 0, stream>>>(x, xn, N, N);
    rownorm_bf16<<<C_PAD / 4, 256, 0, stream>>>(W, Wn, C, C_PAD);

    amsm_gemm<<<8 * CTILES, 512, 0, stream>>>(xn, Wn, lb, psum, tgtv, C, CHUNKS);

    row_reduce<<<N, 256, 0, stream>>>(psum, tgtv, rl, CHUNKS);
    final_reduce<<<1, 256, 0, stream>>>(rl, out, N);
}

// Round 7
// 293.611 us; speedup vs baseline: 1.2688x; 1.2688x over previous
//
#include <hip/hip_runtime.h>
#include <hip/hip_bf16.h>
#include <cfloat>
#include <math.h>

// ---------------- types ----------------
typedef __bf16 bf16x8 __attribute__((ext_vector_type(8)));
typedef float  f32x4  __attribute__((ext_vector_type(4)));

#define AMSM_MARGIN 0.35f
#define AMSM_SCALE  30.0f
#define AMSM_EPS    1e-12f

// ---------------- kernel 1/2: row-normalize f32 -> bf16 ----------------
__global__ __launch_bounds__(256) void rownorm_bf16(
    const float* __restrict__ src, __bf16* __restrict__ dst,
    int nrows, int nrows_pad)
{
    int row  = blockIdx.x * 4 + (threadIdx.x >> 6);
    int lane = threadIdx.x & 63;
    if (row >= nrows_pad) return;

    __bf16* drow = dst + (size_t)row * 512 + lane * 8;

    if (row >= nrows) {           // zero-fill pad rows (keeps MFMA garbage-free)
        bf16x8 z = {};
        *(bf16x8*)drow = z;
        return;
    }
    const float4* p = (const float4*)(src + (size_t)row * 512 + lane * 8);
    float4 a = p[0], b = p[1];
    float ss = a.x*a.x + a.y*a.y + a.z*a.z + a.w*a.w
             + b.x*b.x + b.y*b.y + b.z*b.z + b.w*b.w;
    #pragma unroll
    for (int m = 1; m < 64; m <<= 1) ss += __shfl_xor(ss, m, 64);
    float r = 1.0f / sqrtf(ss + AMSM_EPS);

    bf16x8 o;
    o[0] = (__bf16)(a.x*r); o[1] = (__bf16)(a.y*r);
    o[2] = (__bf16)(a.z*r); o[3] = (__bf16)(a.w*r);
    o[4] = (__bf16)(b.x*r); o[5] = (__bf16)(b.y*r);
    o[6] = (__bf16)(b.z*r); o[7] = (__bf16)(b.w*r);
    *(bf16x8*)drow = o;
}

// ---------------- kernel 3: 128x256 triple-buffered fused GEMM + sum-exp --
// BM=128 (x rows), BN=256 (classes), BK=32, 8 waves (2M x 4N), 64x64/wave.
// Registers: acc 64 + frags 32 -> <=128/wave => 4 waves/SIMD.
// LDS 72KB: A regions 3 x 8KB (rows 128 x 32k), B regions 3 x 16KB (256 x 32k)
//   -> 2 blocks/CU co-resident: cross-block pipe overlap (m114 mechanism).
// Triple buffer = depth-2 prefetch with counted VMC(3) (never drains to 0
// in steady state). Phase t: read buf t%3, stage tile t+2 into buf (t+2)%3.
// T2 swizzle identical to r5/r6 (conflicts measured 0): source k-chunk
// ^((q>>4)&2), read k ^((lo>>2)&2); row stride 64B in both regions.
#define CTILES 391    // 100096 / 256

__device__ __forceinline__ void load_lds16(const void* g, void* l) {
    __builtin_amdgcn_global_load_lds(
        (const __attribute__((address_space(1))) void*)g,
        (__attribute__((address_space(3))) void*)l, 16, 0, 0);
}

#define BAR() __builtin_amdgcn_s_barrier()
#define VMC(N) asm volatile("s_waitcnt vmcnt(" #N ")" ::: "memory")

__global__ __launch_bounds__(512, 4) void amsm_gemm(
    const __bf16* __restrict__ xn, const __bf16* __restrict__ Wn,
    const int* __restrict__ lb,
    float* __restrict__ psum, float* __restrict__ tgt, int C, int CHUNKS)
{
    __shared__ char lds[73728];   // A: [3][8192] at 0; B: [3][16384] at 24576

    // T1: bijective XCD swizzle (6256 = 8 * 782; 6256 = 16 * 391)
    const int bid = blockIdx.x;
    const int wid = (bid & 7) * 782 + (bid >> 3);
    const int mt  = wid & 15;           // m fast -> same-XCD blocks share W band
    const int ct  = wid >> 4;
    const int m0  = mt * 128;
    const int c0  = ct * 256;

    const int tid  = threadIdx.x;
    const int lane = tid & 63;
    const int w    = tid >> 6;
    const int wr   = w >> 2;            // 0..1 (M)
    const int wc   = w & 3;             // 0..3 (N)
    const int g    = lane >> 4;
    const int lo   = lane & 15;

    const __bf16* gA = xn + (size_t)m0 * 512;
    const __bf16* gB = Wn + (size_t)c0 * 512;

    // stage tile kt's A half (8KB, 1 instr/thread) / B half (16KB, 2 instr)
    auto stageA = [&](int b, int kt) {
        const int q   = tid;                        // 512 x 16B = 128 rows x 64B
        const int row = q >> 2;
        const int kc  = (q & 3) ^ ((q >> 4) & 2);   // T2 involution (source)
        load_lds16(gA + (size_t)row * 512 + kt * 32 + kc * 8,
                   lds + b * 8192 + q * 16);
    };
    auto stageB = [&](int b, int kt) {
        #pragma unroll
        for (int iss = 0; iss < 2; ++iss) {
            const int q   = iss * 512 + tid;        // 1024 x 16B = 256 rows x 64B
            const int row = q >> 2;
            const int kc  = (q & 3) ^ ((q >> 4) & 2);
            load_lds16(gB + (size_t)row * 512 + kt * 32 + kc * 8,
                       lds + 24576 + b * 16384 + q * 16);
        }
    };

    const int kxb  = (g ^ ((lo >> 2) & 2)) * 16;    // T2 involution (read), bytes
    const int aoff = (wr * 64 + lo) * 64 + kxb;     // byte off within A region
    const int boff = (wc * 64 + lo) * 64 + kxb;     // within B region

    f32x4  acc[4][4] = {};
    bf16x8 af[4], bfr[4];

#define LDA(B) { const char* rb_ = lds + (B)*8192 + aoff; \
    _Pragma("unroll") for (int mi_ = 0; mi_ < 4; ++mi_) \
        af[mi_] = *(const bf16x8*)(rb_ + mi_*1024); }
#define LDB(B) { const char* rb_ = lds + 24576 + (B)*16384 + boff; \
    _Pragma("unroll") for (int ni_ = 0; ni_ < 4; ++ni_) \
        bfr[ni_] = *(const bf16x8*)(rb_ + ni_*1024); }
#define MM16() __builtin_amdgcn_s_setprio(1); \
    _Pragma("unroll") for (int mi_ = 0; mi_ < 4; ++mi_) \
      _Pragma("unroll") for (int ni_ = 0; ni_ < 4; ++ni_) \
        acc[mi_][ni_] = __builtin_amdgcn_mfma_f32_16x16x32_bf16(af[mi_], bfr[ni_], acc[mi_][ni_], 0,0,0); \
    __builtin_amdgcn_s_setprio(0);
// phase: read BUF; optionally stage tile T2 into SBUF; sync; 16 MFMA; counted wait
#define PH3(BUF, SBUF, T2)  { LDA(BUF); LDB(BUF); stageA(SBUF, T2); stageB(SBUF, T2); \
    BAR(); MM16(); VMC(3); BAR(); }

    // ---- prologue: tiles 0,1 -> bufs 0,1 (6 load instrs; drain tile0 only)
    stageA(0, 0); stageB(0, 0);
    stageA(1, 1); stageB(1, 1);
    VMC(3); BAR();

    // ---- 16 K-steps; phase t reads buf t%3, stages t+2 into (t+2)%3 ----
    PH3(0, 2,  2);   // t=0
    PH3(1, 0,  3);   // t=1
    PH3(2, 1,  4);   // t=2
    PH3(0, 2,  5);   // t=3
    PH3(1, 0,  6);   // t=4
    PH3(2, 1,  7);   // t=5
    PH3(0, 2,  8);   // t=6
    PH3(1, 0,  9);   // t=7
    PH3(2, 1, 10);   // t=8
    PH3(0, 2, 11);   // t=9
    PH3(1, 0, 12);   // t=10
    PH3(2, 1, 13);   // t=11
    PH3(0, 2, 14);   // t=12
    PH3(1, 0, 15);   // t=13
    // t=14: no stage; drain tile15's loads (issued t=13)
    LDA(2); LDB(2); BAR(); MM16(); VMC(0); BAR();
    // t=15: last tile, no stage, no trailing sync needed (regs only after)
    LDA(0); LDB(0); BAR(); MM16();

    // ---- epilogue: C/D map col=lane&15 (class), row=(lane>>4)*4+reg (x-row) ----
    const int n_base = m0 + wr * 64;
    const int c_base = c0 + wc * 64;
    const int chunk  = ct * 4 + wc;

    #pragma unroll
    for (int mi = 0; mi < 4; ++mi) {
        #pragma unroll
        for (int j = 0; j < 4; ++j) {
            const int n = n_base + mi * 16 + g * 4 + j;
            const int target = lb[n];
            float s = 0.f;
            #pragma unroll
            for (int ni = 0; ni < 4; ++ni) {
                const int c = c_base + ni * 16 + lo;
                float logit = AMSM_SCALE * acc[mi][ni][j];
                if (c == target) {
                    logit -= AMSM_SCALE * AMSM_MARGIN;
                    tgt[n] = logit;                    // unique writer globally
                }
                // analytic bound: logit <= SCALE; exp(logit-SCALE) in [2.6e-31, 1]
                s += (c < C) ? __expf(logit - AMSM_SCALE) : 0.f;
            }
            #pragma unroll
            for (int m_ = 1; m_ < 16; m_ <<= 1) s += __shfl_xor(s, m_, 64);
            if (lo == 0) psum[(size_t)n * CHUNKS + chunk] = s;
        }
    }
#undef LDA
#undef LDB
#undef MM16
#undef PH3
}

// ---------------- kernel 4: per-row combine of partials ----------------
__global__ __launch_bounds__(256) void row_reduce(
    const float* __restrict__ psum, const float* __restrict__ tgt,
    float* __restrict__ row_loss, int CHUNKS)
{
    const int n = blockIdx.x;
    const int tid = threadIdx.x;
    __shared__ float sm[256];

    float s = 0.f;
    for (int j = tid; j < CHUNKS; j += 256) s += psum[(size_t)n * CHUNKS + j];
    sm[tid] = s; __syncthreads();
    for (int st = 128; st > 0; st >>= 1) {
        if (tid < st) sm[tid] += sm[tid + st];
        __syncthreads();
    }
    if (tid == 0) row_loss[n] = (logf(sm[0]) + AMSM_SCALE) - tgt[n];
}

// ---------------- kernel 5: mean over rows -> scalar ----------------
__global__ __launch_bounds__(256) void final_reduce(
    const float* __restrict__ row_loss, float* __restrict__ out, int N)
{
    const int tid = threadIdx.x;
    __shared__ float sm[256];
    float s = 0.f;
    for (int i = tid; i < N; i += 256) s += row_loss[i];
    sm[tid] = s; __syncthreads();
    for (int st = 128; st > 0; st >>= 1) {
        if (tid < st) sm[tid] += sm[tid + st];
        __syncthreads();
    }
    if (tid == 0) out[0] = sm[0] / (float)N;
}

// ---------------- launch ----------------
extern "C" void kernel_launch(void* const* d_in, const int* in_sizes, int n_in,
                              void* d_out, int out_size, void* d_ws, size_t ws_size,
                              hipStream_t stream) {
    const float* x  = (const float*)d_in[0];
    const float* W  = (const float*)d_in[1];
    const int*   lb = (const int*)d_in[2];
    float* out = (float*)d_out;

    constexpr int N  = 2048, D = 512, C = 100000;
    constexpr int C_PAD  = CTILES * 256;     // 100096
    constexpr int CHUNKS = CTILES * 4;       // 1564 (one per 64-col wave stripe)

    char* ws = (char*)d_ws;
    auto alloc = [&](size_t bytes) {
        char* p = ws; ws += (bytes + 255) & ~(size_t)255; return p;
    };
    __bf16* Wn   = (__bf16*)alloc((size_t)C_PAD * D * sizeof(__bf16)); // 102.5 MB
    __bf16* xn   = (__bf16*)alloc((size_t)N * D * sizeof(__bf16));     // 2 MB
    float*  psum = (float*)alloc((size_t)N * CHUNKS * sizeof(float));  // 12.8 MB
    float*  tgtv = (float*)alloc((size_t)N * sizeof(float));
    float*  rl   = (float*)alloc((size_t)N * sizeof(float));

    rownorm_bf16<<<N / 4, 256, 0, stream>>>(x, xn, N, N);
    rownorm_bf16<<<C_PAD / 4, 256, 0, stream>>>(W, Wn, C, C_PAD);

    amsm_gemm<<<16 * CTILES, 512, 0, stream>>>(xn, Wn, lb, psum, tgtv, C, CHUNKS);

    row_reduce<<<N, 256, 0, stream>>>(psum, tgtv, rl, CHUNKS);
    final_reduce<<<1, 256, 0, stream>>>(rl, out, N);
}

// Round 8
// 289.817 us; speedup vs baseline: 1.2855x; 1.0131x over previous
//
#include <hip/hip_runtime.h>
#include <hip/hip_bf16.h>
#include <cfloat>
#include <math.h>

// ---------------- types ----------------
typedef __bf16 bf16x8 __attribute__((ext_vector_type(8)));
typedef float  f32x4  __attribute__((ext_vector_type(4)));

#define AMSM_MARGIN 0.35f
#define AMSM_SCALE  30.0f
#define AMSM_EPS    1e-12f

// ---------------- kernel 1/2: row-normalize f32 -> bf16 ----------------
__global__ __launch_bounds__(256) void rownorm_bf16(
    const float* __restrict__ src, __bf16* __restrict__ dst,
    int nrows, int nrows_pad)
{
    int row  = blockIdx.x * 4 + (threadIdx.x >> 6);
    int lane = threadIdx.x & 63;
    if (row >= nrows_pad) return;

    __bf16* drow = dst + (size_t)row * 512 + lane * 8;

    if (row >= nrows) {           // zero-fill pad rows (keeps MFMA garbage-free)
        bf16x8 z = {};
        *(bf16x8*)drow = z;
        return;
    }
    const float4* p = (const float4*)(src + (size_t)row * 512 + lane * 8);
    float4 a = p[0], b = p[1];
    float ss = a.x*a.x + a.y*a.y + a.z*a.z + a.w*a.w
             + b.x*b.x + b.y*b.y + b.z*b.z + b.w*b.w;
    #pragma unroll
    for (int m = 1; m < 64; m <<= 1) ss += __shfl_xor(ss, m, 64);
    float r = 1.0f / sqrtf(ss + AMSM_EPS);

    bf16x8 o;
    o[0] = (__bf16)(a.x*r); o[1] = (__bf16)(a.y*r);
    o[2] = (__bf16)(a.z*r); o[3] = (__bf16)(a.w*r);
    o[4] = (__bf16)(b.x*r); o[5] = (__bf16)(b.y*r);
    o[6] = (__bf16)(b.z*r); o[7] = (__bf16)(b.w*r);
    *(bf16x8*)drow = o;
}

// ---------------- kernel 3: 128x256 triple-buffered fused GEMM + sum-exp --
// Same geometry as r7 (BM=128, BN=256, BK=32, 8 waves 2Mx4N, 64x64/wave,
// LDS 72KB triple-buffered, 2 blocks/CU). ONE change vs r7: the mid-phase
// barrier is REMOVED. Phase = {8 ds_read, 3 global_load_lds, MFMA (lgkm-
// auto-drained), VMC(3), BAR}. Buffer safety audit: a wave's phase-t
// ds_reads are drained by its MFMA before it reaches the end BAR; the stage
// overwriting buf t%3 is issued at phase t+1 (post-BAR); stage->read
// distance (2 phases) is drained by VMC(3) one phase after issue. Waves can
// now skew WITHIN a phase -> LDS port and MFMA pipe overlap instead of
// alternating in lockstep (r6/r7's ~47% alternation ceiling).
#define CTILES 391    // 100096 / 256

__device__ __forceinline__ void load_lds16(const void* g, void* l) {
    __builtin_amdgcn_global_load_lds(
        (const __attribute__((address_space(1))) void*)g,
        (__attribute__((address_space(3))) void*)l, 16, 0, 0);
}

#define BAR() __builtin_amdgcn_s_barrier()
#define VMC(N) asm volatile("s_waitcnt vmcnt(" #N ")" ::: "memory")

__global__ __launch_bounds__(512, 4) void amsm_gemm(
    const __bf16* __restrict__ xn, const __bf16* __restrict__ Wn,
    const int* __restrict__ lb,
    float* __restrict__ psum, float* __restrict__ tgt, int C, int CHUNKS)
{
    __shared__ char lds[73728];   // A: [3][8192] at 0; B: [3][16384] at 24576

    // T1: bijective XCD swizzle (6256 = 8 * 782; 6256 = 16 * 391)
    const int bid = blockIdx.x;
    const int wid = (bid & 7) * 782 + (bid >> 3);
    const int mt  = wid & 15;           // m fast -> same-XCD blocks share W band
    const int ct  = wid >> 4;
    const int m0  = mt * 128;
    const int c0  = ct * 256;

    const int tid  = threadIdx.x;
    const int lane = tid & 63;
    const int w    = tid >> 6;
    const int wr   = w >> 2;            // 0..1 (M)
    const int wc   = w & 3;             // 0..3 (N)
    const int g    = lane >> 4;
    const int lo   = lane & 15;

    const __bf16* gA = xn + (size_t)m0 * 512;
    const __bf16* gB = Wn + (size_t)c0 * 512;

    // stage tile kt's A half (8KB, 1 instr/thread) / B half (16KB, 2 instr)
    auto stageA = [&](int b, int kt) {
        const int q   = tid;                        // 512 x 16B = 128 rows x 64B
        const int row = q >> 2;
        const int kc  = (q & 3) ^ ((q >> 4) & 2);   // T2 involution (source)
        load_lds16(gA + (size_t)row * 512 + kt * 32 + kc * 8,
                   lds + b * 8192 + q * 16);
    };
    auto stageB = [&](int b, int kt) {
        #pragma unroll
        for (int iss = 0; iss < 2; ++iss) {
            const int q   = iss * 512 + tid;        // 1024 x 16B = 256 rows x 64B
            const int row = q >> 2;
            const int kc  = (q & 3) ^ ((q >> 4) & 2);
            load_lds16(gB + (size_t)row * 512 + kt * 32 + kc * 8,
                       lds + 24576 + b * 16384 + q * 16);
        }
    };

    const int kxb  = (g ^ ((lo >> 2) & 2)) * 16;    // T2 involution (read), bytes
    const int aoff = (wr * 64 + lo) * 64 + kxb;     // byte off within A region
    const int boff = (wc * 64 + lo) * 64 + kxb;     // within B region

    f32x4  acc[4][4] = {};
    bf16x8 af[4], bfr[4];

#define LDA(B) { const char* rb_ = lds + (B)*8192 + aoff; \
    _Pragma("unroll") for (int mi_ = 0; mi_ < 4; ++mi_) \
        af[mi_] = *(const bf16x8*)(rb_ + mi_*1024); }
#define LDB(B) { const char* rb_ = lds + 24576 + (B)*16384 + boff; \
    _Pragma("unroll") for (int ni_ = 0; ni_ < 4; ++ni_) \
        bfr[ni_] = *(const bf16x8*)(rb_ + ni_*1024); }
#define MM16() __builtin_amdgcn_s_setprio(1); \
    _Pragma("unroll") for (int mi_ = 0; mi_ < 4; ++mi_) \
      _Pragma("unroll") for (int ni_ = 0; ni_ < 4; ++ni_) \
        acc[mi_][ni_] = __builtin_amdgcn_mfma_f32_16x16x32_bf16(af[mi_], bfr[ni_], acc[mi_][ni_], 0,0,0); \
    __builtin_amdgcn_s_setprio(0);
// phase: read BUF; stage tile T2 into SBUF; MFMA (lgkm auto-drain);
// counted wait; ONE barrier (buffer-safety only -- no mid-phase lockstep)
#define PH3(BUF, SBUF, T2)  { LDA(BUF); LDB(BUF); stageA(SBUF, T2); stageB(SBUF, T2); \
    MM16(); VMC(3); BAR(); }

    // ---- prologue: tiles 0,1 -> bufs 0,1 (6 load instrs; drain tile0 only)
    stageA(0, 0); stageB(0, 0);
    stageA(1, 1); stageB(1, 1);
    VMC(3); BAR();

    // ---- 16 K-steps; phase t reads buf t%3, stages t+2 into (t+2)%3 ----
    PH3(0, 2,  2);   // t=0
    PH3(1, 0,  3);   // t=1
    PH3(2, 1,  4);   // t=2
    PH3(0, 2,  5);   // t=3
    PH3(1, 0,  6);   // t=4
    PH3(2, 1,  7);   // t=5
    PH3(0, 2,  8);   // t=6
    PH3(1, 0,  9);   // t=7
    PH3(2, 1, 10);   // t=8
    PH3(0, 2, 11);   // t=9
    PH3(1, 0, 12);   // t=10
    PH3(2, 1, 13);   // t=11
    PH3(0, 2, 14);   // t=12
    PH3(1, 0, 15);   // t=13
    // t=14: no stage; drain tile15's loads (issued t=13)
    LDA(2); LDB(2); MM16(); VMC(0); BAR();
    // t=15: last tile, no stage, no trailing sync needed (regs only after)
    LDA(0); LDB(0); MM16();

    // ---- epilogue: C/D map col=lane&15 (class), row=(lane>>4)*4+reg (x-row) ----
    const int n_base = m0 + wr * 64;
    const int c_base = c0 + wc * 64;
    const int chunk  = ct * 4 + wc;

    #pragma unroll
    for (int mi = 0; mi < 4; ++mi) {
        #pragma unroll
        for (int j = 0; j < 4; ++j) {
            const int n = n_base + mi * 16 + g * 4 + j;
            const int target = lb[n];
            float s = 0.f;
            #pragma unroll
            for (int ni = 0; ni < 4; ++ni) {
                const int c = c_base + ni * 16 + lo;
                float logit = AMSM_SCALE * acc[mi][ni][j];
                if (c == target) {
                    logit -= AMSM_SCALE * AMSM_MARGIN;
                    tgt[n] = logit;                    // unique writer globally
                }
                // analytic bound: logit <= SCALE; exp(logit-SCALE) in [2.6e-31, 1]
                s += (c < C) ? __expf(logit - AMSM_SCALE) : 0.f;
            }
            #pragma unroll
            for (int m_ = 1; m_ < 16; m_ <<= 1) s += __shfl_xor(s, m_, 64);
            if (lo == 0) psum[(size_t)n * CHUNKS + chunk] = s;
        }
    }
#undef LDA
#undef LDB
#undef MM16
#undef PH3
}

// ---------------- kernel 4: per-row combine of partials ----------------
__global__ __launch_bounds__(256) void row_reduce(
    const float* __restrict__ psum, const float* __restrict__ tgt,
    float* __restrict__ row_loss, int CHUNKS)
{
    const int n = blockIdx.x;
    const int tid = threadIdx.x;
    __shared__ float sm[256];

    float s = 0.f;
    for (int j = tid; j < CHUNKS; j += 256) s += psum[(size_t)n * CHUNKS + j];
    sm[tid] = s; __syncthreads();
    for (int st = 128; st > 0; st >>= 1) {
        if (tid < st) sm[tid] += sm[tid + st];
        __syncthreads();
    }
    if (tid == 0) row_loss[n] = (logf(sm[0]) + AMSM_SCALE) - tgt[n];
}

// ---------------- kernel 5: mean over rows -> scalar ----------------
__global__ __launch_bounds__(256) void final_reduce(
    const float* __restrict__ row_loss, float* __restrict__ out, int N)
{
    const int tid = threadIdx.x;
    __shared__ float sm[256];
    float s = 0.f;
    for (int i = tid; i < N; i += 256) s += row_loss[i];
    sm[tid] = s; __syncthreads();
    for (int st = 128; st > 0; st >>= 1) {
        if (tid < st) sm[tid] += sm[tid + st];
        __syncthreads();
    }
    if (tid == 0) out[0] = sm[0] / (float)N;
}

// ---------------- launch ----------------
extern "C" void kernel_launch(void* const* d_in, const int* in_sizes, int n_in,
                              void* d_out, int out_size, void* d_ws, size_t ws_size,
                              hipStream_t stream) {
    const float* x  = (const float*)d_in[0];
    const float* W  = (const float*)d_in[1];
    const int*   lb = (const int*)d_in[2];
    float* out = (float*)d_out;

    constexpr int N  = 2048, D = 512, C = 100000;
    constexpr int C_PAD  = CTILES * 256;     // 100096
    constexpr int CHUNKS = CTILES * 4;       // 1564 (one per 64-col wave stripe)

    char* ws = (char*)d_ws;
    auto alloc = [&](size_t bytes) {
        char* p = ws; ws += (bytes + 255) & ~(size_t)255; return p;
    };
    __bf16* Wn   = (__bf16*)alloc((size_t)C_PAD * D * sizeof(__bf16)); // 102.5 MB
    __bf16* xn   = (__bf16*)alloc((size_t)N * D * sizeof(__bf16));     // 2 MB
    float*  psum = (float*)alloc((size_t)N * CHUNKS * sizeof(float));  // 12.8 MB
    float*  tgtv = (float*)alloc((size_t)N * sizeof(float));
    float*  rl   = (float*)alloc((size_t)N * sizeof(float));

    rownorm_bf16<<<N / 4, 256, 0, stream>>>(x, xn, N, N);
    rownorm_bf16<<<C_PAD / 4, 256, 0, stream>>>(W, Wn, C, C_PAD);

    amsm_gemm<<<16 * CTILES, 512, 0, stream>>>(xn, Wn, lb, psum, tgtv, C, CHUNKS);

    row_reduce<<<N, 256, 0, stream>>>(psum, tgtv, rl, CHUNKS);
    final_reduce<<<1, 256, 0, stream>>>(rl, out, N);
}

// Round 9
// 212.340 us; speedup vs baseline: 1.7545x; 1.3649x over previous
//
#include <hip/hip_runtime.h>
#include <hip/hip_bf16.h>
#include <cfloat>
#include <math.h>

// ---------------- types ----------------
typedef int   int32x4 __attribute__((ext_vector_type(4)));

#define AMSM_MARGIN 0.35f
#define AMSM_SCALE  30.0f
#define AMSM_EPS    1e-12f

// ------------- kernel 1/2: row-normalize f32 -> per-row-scaled i8 ---------
// one wave per row: unit-normalize, find rowmax, quantize q=round(v*127/m),
// store scale[row] = m/127 (dequant factor). Integer GEMM is then EXACT;
// the only approximation is this input quantization (est. loss err ~0.03).
__global__ __launch_bounds__(256) void rownorm_i8(
    const float* __restrict__ src, signed char* __restrict__ dst,
    float* __restrict__ scale, int nrows, int nrows_pad)
{
    int row  = blockIdx.x * 4 + (threadIdx.x >> 6);
    int lane = threadIdx.x & 63;
    if (row >= nrows_pad) return;

    signed char* drow = dst + (size_t)row * 512 + lane * 8;

    if (row >= nrows) {           // zero-fill pad rows
        *(int2*)drow = make_int2(0, 0);
        if (lane == 0) scale[row] = 0.f;
        return;
    }
    const float4* p = (const float4*)(src + (size_t)row * 512 + lane * 8);
    float4 a = p[0], b = p[1];
    float ss = a.x*a.x + a.y*a.y + a.z*a.z + a.w*a.w
             + b.x*b.x + b.y*b.y + b.z*b.z + b.w*b.w;
    #pragma unroll
    for (int m = 1; m < 64; m <<= 1) ss += __shfl_xor(ss, m, 64);
    float r = 1.0f / sqrtf(ss + AMSM_EPS);

    float v[8] = { a.x*r, a.y*r, a.z*r, a.w*r, b.x*r, b.y*r, b.z*r, b.w*r };
    float mx = 0.f;
    #pragma unroll
    for (int i = 0; i < 8; ++i) mx = fmaxf(mx, fabsf(v[i]));
    #pragma unroll
    for (int m = 1; m < 64; m <<= 1) mx = fmaxf(mx, __shfl_xor(mx, m, 64));
    // mx >= 1/sqrt(512) > 0 for a unit vector
    float qs = 127.0f / mx;

    int q[8];
    #pragma unroll
    for (int i = 0; i < 8; ++i) {
        float t = rintf(v[i] * qs);
        t = fmaxf(-127.f, fminf(127.f, t));
        q[i] = (int)t;
    }
    unsigned int lo32 = (q[0]&255) | ((q[1]&255)<<8) | ((q[2]&255)<<16) | ((unsigned)(q[3]&255)<<24);
    unsigned int hi32 = (q[4]&255) | ((q[5]&255)<<8) | ((q[6]&255)<<16) | ((unsigned)(q[7]&255)<<24);
    *(int2*)drow = make_int2((int)lo32, (int)hi32);
    if (lane == 0) scale[row] = mx * (1.0f / 127.0f);
}

// ---------------- kernel 3: 128x256 i8 triple-buffered GEMM + sum-exp -----
// Geometry identical to r8 in BYTES (A regions 3x8KB of [128][64B], B 3x16KB
// of [256][64B], 8 waves 2Mx4N, 64x64/wave, 2 blocks/CU) but dtype i8:
// one 64B row = 64 k-elements -> BK=64, 8 phases, 16x16x64 i8 MFMA (2x bf16
// rate, half LDS traffic). acc is EXACT i32. T2 swizzle formulas unchanged
// (byte-level identical; measured conflicts 0 in r5-r8).
#define CTILES 391    // 100096 / 256

__device__ __forceinline__ void load_lds16(const void* g, void* l) {
    __builtin_amdgcn_global_load_lds(
        (const __attribute__((address_space(1))) void*)g,
        (__attribute__((address_space(3))) void*)l, 16, 0, 0);
}

#define BAR() __builtin_amdgcn_s_barrier()
#define VMC(N) asm volatile("s_waitcnt vmcnt(" #N ")" ::: "memory")

__global__ __launch_bounds__(512, 4) void amsm_gemm(
    const signed char* __restrict__ xq, const signed char* __restrict__ Wq,
    const float* __restrict__ sa, const float* __restrict__ sb,
    const int* __restrict__ lb,
    float* __restrict__ psum, float* __restrict__ tgt, int C, int CHUNKS)
{
    __shared__ char lds[73728];   // A: [3][8192] at 0; B: [3][16384] at 24576

    // T1: bijective XCD swizzle (6256 = 8 * 782)
    const int bid = blockIdx.x;
    const int wid = (bid & 7) * 782 + (bid >> 3);
    const int mt  = wid & 15;           // m fast -> same-XCD blocks share W band
    const int ct  = wid >> 4;
    const int m0  = mt * 128;
    const int c0  = ct * 256;

    const int tid  = threadIdx.x;
    const int lane = tid & 63;
    const int w    = tid >> 6;
    const int wr   = w >> 2;            // 0..1 (M)
    const int wc   = w & 3;             // 0..3 (N)
    const int g    = lane >> 4;
    const int lo   = lane & 15;

    const signed char* gA = xq + (size_t)m0 * 512;
    const signed char* gB = Wq + (size_t)c0 * 512;

    // stage tile kt (64 k-bytes/row): A 8KB (1 instr/thread), B 16KB (2)
    auto stageA = [&](int b, int kt) {
        const int q   = tid;                        // 512 x 16B = 128 rows x 64B
        const int row = q >> 2;
        const int kc  = (q & 3) ^ ((q >> 4) & 2);   // T2 involution (source)
        load_lds16(gA + (size_t)row * 512 + kt * 64 + kc * 16,
                   lds + b * 8192 + q * 16);
    };
    auto stageB = [&](int b, int kt) {
        #pragma unroll
        for (int iss = 0; iss < 2; ++iss) {
            const int q   = iss * 512 + tid;        // 1024 x 16B = 256 rows x 64B
            const int row = q >> 2;
            const int kc  = (q & 3) ^ ((q >> 4) & 2);
            load_lds16(gB + (size_t)row * 512 + kt * 64 + kc * 16,
                       lds + 24576 + b * 16384 + q * 16);
        }
    };

    const int kxb  = (g ^ ((lo >> 2) & 2)) * 16;    // T2 involution (read), bytes
    const int aoff = (wr * 64 + lo) * 64 + kxb;     // byte off within A region
    const int boff = (wc * 64 + lo) * 64 + kxb;     // within B region

    int32x4 acc[4][4] = {};
    int32x4 af[4], bfr[4];

#define LDA(B) { const char* rb_ = lds + (B)*8192 + aoff; \
    _Pragma("unroll") for (int mi_ = 0; mi_ < 4; ++mi_) \
        af[mi_] = *(const int32x4*)(rb_ + mi_*1024); }
#define LDB(B) { const char* rb_ = lds + 24576 + (B)*16384 + boff; \
    _Pragma("unroll") for (int ni_ = 0; ni_ < 4; ++ni_) \
        bfr[ni_] = *(const int32x4*)(rb_ + ni_*1024); }
#define MM16() __builtin_amdgcn_s_setprio(1); \
    _Pragma("unroll") for (int mi_ = 0; mi_ < 4; ++mi_) \
      _Pragma("unroll") for (int ni_ = 0; ni_ < 4; ++ni_) \
        acc[mi_][ni_] = __builtin_amdgcn_mfma_i32_16x16x64_i8(af[mi_], bfr[ni_], acc[mi_][ni_], 0,0,0); \
    __builtin_amdgcn_s_setprio(0);
#define PH3(BUF, SBUF, T2)  { LDA(BUF); LDB(BUF); stageA(SBUF, T2); stageB(SBUF, T2); \
    MM16(); VMC(3); BAR(); }

    // ---- prologue: tiles 0,1 -> bufs 0,1 (6 loads; drain tile0's 3) ----
    stageA(0, 0); stageB(0, 0);
    stageA(1, 1); stageB(1, 1);
    VMC(3); BAR();

    // ---- 8 K-steps (BK=64); phase t reads buf t%3, stages t+2 -> (t+2)%3 --
    PH3(0, 2, 2);   // t=0
    PH3(1, 0, 3);   // t=1
    PH3(2, 1, 4);   // t=2
    PH3(0, 2, 5);   // t=3
    PH3(1, 0, 6);   // t=4
    PH3(2, 1, 7);   // t=5
    // t=6: no stage; drain tile7 (issued t=5)
    LDA(0); LDB(0); MM16(); VMC(0); BAR();
    // t=7: last tile
    LDA(1); LDB(1); MM16();

    // ---- epilogue: C/D col=lane&15 (class), row=(lane>>4)*4+reg (x-row) ---
    const int n_base = m0 + wr * 64;
    const int c_base = c0 + wc * 64;
    const int chunk  = ct * 4 + wc;

    float sbv[4];
    #pragma unroll
    for (int ni = 0; ni < 4; ++ni) sbv[ni] = sb[c_base + ni * 16 + lo];

    #pragma unroll
    for (int mi = 0; mi < 4; ++mi) {
        #pragma unroll
        for (int j = 0; j < 4; ++j) {
            const int n = n_base + mi * 16 + g * 4 + j;
            const int target = lb[n];
            const float st = AMSM_SCALE * sa[n];
            float s = 0.f;
            #pragma unroll
            for (int ni = 0; ni < 4; ++ni) {
                const int c = c_base + ni * 16 + lo;
                float logit = st * sbv[ni] * (float)acc[mi][ni][j];
                if (c == target) {
                    logit -= AMSM_SCALE * AMSM_MARGIN;
                    tgt[n] = logit;                    // unique writer globally
                }
                // logit <= ~30.05 (quant err); exp(logit-30) in [2.6e-31, ~1.05]
                s += (c < C) ? __expf(logit - AMSM_SCALE) : 0.f;
            }
            #pragma unroll
            for (int m_ = 1; m_ < 16; m_ <<= 1) s += __shfl_xor(s, m_, 64);
            if (lo == 0) psum[(size_t)n * CHUNKS + chunk] = s;
        }
    }
#undef LDA
#undef LDB
#undef MM16
#undef PH3
}

// ---------------- kernel 4: per-row combine of partials ----------------
__global__ __launch_bounds__(256) void row_reduce(
    const float* __restrict__ psum, const float* __restrict__ tgt,
    float* __restrict__ row_loss, int CHUNKS)
{
    const int n = blockIdx.x;
    const int tid = threadIdx.x;
    __shared__ float sm[256];

    float s = 0.f;
    for (int j = tid; j < CHUNKS; j += 256) s += psum[(size_t)n * CHUNKS + j];
    sm[tid] = s; __syncthreads();
    for (int st = 128; st > 0; st >>= 1) {
        if (tid < st) sm[tid] += sm[tid + st];
        __syncthreads();
    }
    if (tid == 0) row_loss[n] = (logf(sm[0]) + AMSM_SCALE) - tgt[n];
}

// ---------------- kernel 5: mean over rows -> scalar ----------------
__global__ __launch_bounds__(256) void final_reduce(
    const float* __restrict__ row_loss, float* __restrict__ out, int N)
{
    const int tid = threadIdx.x;
    __shared__ float sm[256];
    float s = 0.f;
    for (int i = tid; i < N; i += 256) s += row_loss[i];
    sm[tid] = s; __syncthreads();
    for (int st = 128; st > 0; st >>= 1) {
        if (tid < st) sm[tid] += sm[tid + st];
        __syncthreads();
    }
    if (tid == 0) out[0] = sm[0] / (float)N;
}

// ---------------- launch ----------------
extern "C" void kernel_launch(void* const* d_in, const int* in_sizes, int n_in,
                              void* d_out, int out_size, void* d_ws, size_t ws_size,
                              hipStream_t stream) {
    const float* x  = (const float*)d_in[0];
    const float* W  = (const float*)d_in[1];
    const int*   lb = (const int*)d_in[2];
    float* out = (float*)d_out;

    constexpr int N  = 2048, D = 512, C = 100000;
    constexpr int C_PAD  = CTILES * 256;     // 100096
    constexpr int CHUNKS = CTILES * 4;       // 1564 (one per 64-col wave stripe)

    char* ws = (char*)d_ws;
    auto alloc = [&](size_t bytes) {
        char* p = ws; ws += (bytes + 255) & ~(size_t)255; return p;
    };
    signed char* Wq  = (signed char*)alloc((size_t)C_PAD * D);          // 51.2 MB
    signed char* xqv = (signed char*)alloc((size_t)N * D);              // 1 MB
    float*  sw   = (float*)alloc((size_t)C_PAD * sizeof(float));        // 400 KB
    float*  sx   = (float*)alloc((size_t)N * sizeof(float));
    float*  psum = (float*)alloc((size_t)N * CHUNKS * sizeof(float));   // 12.8 MB
    float*  tgtv = (float*)alloc((size_t)N * sizeof(float));
    float*  rl   = (float*)alloc((size_t)N * sizeof(float));

    rownorm_i8<<<N / 4, 256, 0, stream>>>(x, xqv, sx, N, N);
    rownorm_i8<<<C_PAD / 4, 256, 0, stream>>>(W, Wq, sw, C, C_PAD);

    amsm_gemm<<<16 * CTILES, 512, 0, stream>>>(xqv, Wq, sx, sw, lb, psum, tgtv, C, CHUNKS);

    row_reduce<<<N, 256, 0, stream>>>(psum, tgtv, rl, CHUNKS);
    final_reduce<<<1, 256, 0, stream>>>(rl, out, N);
}

// Round 10
// 188.467 us; speedup vs baseline: 1.9767x; 1.1267x over previous
//
#include <hip/hip_runtime.h>
#include <hip/hip_bf16.h>
#include <cfloat>
#include <math.h>

// ---------------- types ----------------
typedef int   int32x4 __attribute__((ext_vector_type(4)));

#define AMSM_MARGIN 0.35f
#define AMSM_SCALE  30.0f
#define AMSM_EPS    1e-12f
#define L2E         1.4426950408889634f
#define BEXP        (-AMSM_SCALE * L2E)          // exp(logit-30) = exp2(f*acc + BEXP)
#define PADC        8.9833181e-12f               // 96 * exp(-30): pad-column constant

// ------------- kernel 1/2: row-normalize f32 -> per-row-scaled i8 ---------
__global__ __launch_bounds__(256) void rownorm_i8(
    const float* __restrict__ src, signed char* __restrict__ dst,
    float* __restrict__ scale, int nrows, int nrows_pad)
{
    int row  = blockIdx.x * 4 + (threadIdx.x >> 6);
    int lane = threadIdx.x & 63;
    if (row >= nrows_pad) return;

    signed char* drow = dst + (size_t)row * 512 + lane * 8;

    if (row >= nrows) {           // zero-fill pad rows
        *(int2*)drow = make_int2(0, 0);
        if (lane == 0) scale[row] = 0.f;
        return;
    }
    const float4* p = (const float4*)(src + (size_t)row * 512 + lane * 8);
    float4 a = p[0], b = p[1];
    float ss = a.x*a.x + a.y*a.y + a.z*a.z + a.w*a.w
             + b.x*b.x + b.y*b.y + b.z*b.z + b.w*b.w;
    #pragma unroll
    for (int m = 1; m < 64; m <<= 1) ss += __shfl_xor(ss, m, 64);
    float r = 1.0f / sqrtf(ss + AMSM_EPS);

    float v[8] = { a.x*r, a.y*r, a.z*r, a.w*r, b.x*r, b.y*r, b.z*r, b.w*r };
    float mx = 0.f;
    #pragma unroll
    for (int i = 0; i < 8; ++i) mx = fmaxf(mx, fabsf(v[i]));
    #pragma unroll
    for (int m = 1; m < 64; m <<= 1) mx = fmaxf(mx, __shfl_xor(mx, m, 64));
    float qs = 127.0f / mx;       // mx >= 1/sqrt(512) > 0 for a unit vector

    int q[8];
    #pragma unroll
    for (int i = 0; i < 8; ++i) {
        float t = rintf(v[i] * qs);
        t = fmaxf(-127.f, fminf(127.f, t));
        q[i] = (int)t;
    }
    unsigned int lo32 = (q[0]&255) | ((q[1]&255)<<8) | ((q[2]&255)<<16) | ((unsigned)(q[3]&255)<<24);
    unsigned int hi32 = (q[4]&255) | ((q[5]&255)<<8) | ((q[6]&255)<<16) | ((unsigned)(q[7]&255)<<24);
    *(int2*)drow = make_int2((int)lo32, (int)hi32);
    if (lane == 0) scale[row] = mx * (1.0f / 127.0f);
}

// ------------- kernel 2b: exact target logit (margined) per row -----------
// one wave per row: tl = 30*sa[n]*sb[c]*dot(xq[n],Wq[c]) - 10.5
__global__ __launch_bounds__(256) void target_logit(
    const signed char* __restrict__ xq, const signed char* __restrict__ Wq,
    const float* __restrict__ sa, const float* __restrict__ sb,
    const int* __restrict__ lb, float* __restrict__ tgt, int N)
{
    int n    = blockIdx.x * 4 + (threadIdx.x >> 6);
    int lane = threadIdx.x & 63;
    if (n >= N) return;
    const int c = lb[n];
    int2 a = *(const int2*)(xq + (size_t)n * 512 + lane * 8);
    int2 b = *(const int2*)(Wq + (size_t)c * 512 + lane * 8);
    int d = 0;
    #pragma unroll
    for (int i = 0; i < 4; ++i)
        d += ((a.x << (24 - 8*i)) >> 24) * ((b.x << (24 - 8*i)) >> 24);
    #pragma unroll
    for (int i = 0; i < 4; ++i)
        d += ((a.y << (24 - 8*i)) >> 24) * ((b.y << (24 - 8*i)) >> 24);
    #pragma unroll
    for (int m = 1; m < 64; m <<= 1) d += __shfl_xor(d, m, 64);
    if (lane == 0)
        tgt[n] = AMSM_SCALE * sa[n] * sb[c] * (float)d - AMSM_SCALE * AMSM_MARGIN;
}

// ---------------- kernel 3: 128x256 i8 triple-buffered GEMM + sum-exp -----
// Geometry/schedule identical to r9. Epilogue minimized: no lb/target/c<C
// handling (hoisted to target_logit + row_reduce constants); per logit =
// cvt + fma + exp2 + add; 16-row reduce via value-halving butterfly
// (15 shfl vs 64), lane lo ends owning row lo; all 16 lanes store.
#define CTILES 391    // 100096 / 256

__device__ __forceinline__ void load_lds16(const void* g, void* l) {
    __builtin_amdgcn_global_load_lds(
        (const __attribute__((address_space(1))) void*)g,
        (__attribute__((address_space(3))) void*)l, 16, 0, 0);
}

#define BAR() __builtin_amdgcn_s_barrier()
#define VMC(N) asm volatile("s_waitcnt vmcnt(" #N ")" ::: "memory")

__global__ __launch_bounds__(512, 4) void amsm_gemm(
    const signed char* __restrict__ xq, const signed char* __restrict__ Wq,
    const float* __restrict__ sa, const float* __restrict__ sb,
    float* __restrict__ psum, int CHUNKS)
{
    __shared__ char lds[73728];   // A: [3][8192] at 0; B: [3][16384] at 24576

    // T1: bijective XCD swizzle (6256 = 8 * 782)
    const int bid = blockIdx.x;
    const int wid = (bid & 7) * 782 + (bid >> 3);
    const int mt  = wid & 15;           // m fast -> same-XCD blocks share W band
    const int ct  = wid >> 4;
    const int m0  = mt * 128;
    const int c0  = ct * 256;

    const int tid  = threadIdx.x;
    const int lane = tid & 63;
    const int w    = tid >> 6;
    const int wr   = w >> 2;            // 0..1 (M)
    const int wc   = w & 3;             // 0..3 (N)
    const int g    = lane >> 4;
    const int lo   = lane & 15;

    const signed char* gA = xq + (size_t)m0 * 512;
    const signed char* gB = Wq + (size_t)c0 * 512;

    auto stageA = [&](int b, int kt) {
        const int q   = tid;                        // 512 x 16B = 128 rows x 64B
        const int row = q >> 2;
        const int kc  = (q & 3) ^ ((q >> 4) & 2);   // T2 involution (source)
        load_lds16(gA + (size_t)row * 512 + kt * 64 + kc * 16,
                   lds + b * 8192 + q * 16);
    };
    auto stageB = [&](int b, int kt) {
        #pragma unroll
        for (int iss = 0; iss < 2; ++iss) {
            const int q   = iss * 512 + tid;        // 1024 x 16B = 256 rows x 64B
            const int row = q >> 2;
            const int kc  = (q & 3) ^ ((q >> 4) & 2);
            load_lds16(gB + (size_t)row * 512 + kt * 64 + kc * 16,
                       lds + 24576 + b * 16384 + q * 16);
        }
    };

    const int kxb  = (g ^ ((lo >> 2) & 2)) * 16;    // T2 involution (read), bytes
    const int aoff = (wr * 64 + lo) * 64 + kxb;     // byte off within A region
    const int boff = (wc * 64 + lo) * 64 + kxb;     // within B region

    int32x4 acc[4][4] = {};
    int32x4 af[4], bfr[4];

#define LDA(B) { const char* rb_ = lds + (B)*8192 + aoff; \
    _Pragma("unroll") for (int mi_ = 0; mi_ < 4; ++mi_) \
        af[mi_] = *(const int32x4*)(rb_ + mi_*1024); }
#define LDB(B) { const char* rb_ = lds + 24576 + (B)*16384 + boff; \
    _Pragma("unroll") for (int ni_ = 0; ni_ < 4; ++ni_) \
        bfr[ni_] = *(const int32x4*)(rb_ + ni_*1024); }
#define MM16() __builtin_amdgcn_s_setprio(1); \
    _Pragma("unroll") for (int mi_ = 0; mi_ < 4; ++mi_) \
      _Pragma("unroll") for (int ni_ = 0; ni_ < 4; ++ni_) \
        acc[mi_][ni_] = __builtin_amdgcn_mfma_i32_16x16x64_i8(af[mi_], bfr[ni_], acc[mi_][ni_], 0,0,0); \
    __builtin_amdgcn_s_setprio(0);
#define PH3(BUF, SBUF, T2)  { LDA(BUF); LDB(BUF); stageA(SBUF, T2); stageB(SBUF, T2); \
    MM16(); VMC(3); BAR(); }

    // ---- prologue: tiles 0,1 -> bufs 0,1 (6 loads; drain tile0's 3) ----
    stageA(0, 0); stageB(0, 0);
    stageA(1, 1); stageB(1, 1);
    VMC(3); BAR();

    // ---- 8 K-steps (BK=64); phase t reads buf t%3, stages t+2 -> (t+2)%3 --
    PH3(0, 2, 2);   // t=0
    PH3(1, 0, 3);   // t=1
    PH3(2, 1, 4);   // t=2
    PH3(0, 2, 5);   // t=3
    PH3(1, 0, 6);   // t=4
    PH3(2, 1, 7);   // t=5
    LDA(0); LDB(0); MM16(); VMC(0); BAR();   // t=6 (drain tile7)
    LDA(1); LDB(1); MM16();                  // t=7

    // ---- epilogue ----
    const int n_base = m0 + wr * 64;
    const int c_base = c0 + wc * 64;
    const int chunk  = ct * 4 + wc;

    float sbv[4];
    #pragma unroll
    for (int ni = 0; ni < 4; ++ni) sbv[ni] = sb[c_base + ni * 16 + lo];

    // v16[r], r = mi*4+j  <->  row n = n_base + (r>>2)*16 + g*4 + (r&3)
    float v16[16];
    #pragma unroll
    for (int mi = 0; mi < 4; ++mi) {
        float4 sa4 = *(const float4*)(sa + n_base + mi * 16 + g * 4);
        const float* sap = (const float*)&sa4;
        #pragma unroll
        for (int j = 0; j < 4; ++j) {
            const float stf = (AMSM_SCALE * L2E) * sap[j];
            float s = 0.f;
            #pragma unroll
            for (int ni = 0; ni < 4; ++ni)
                s += exp2f(fmaf((float)acc[mi][ni][j], stf * sbv[ni], BEXP));
            v16[mi * 4 + j] = s;
        }
    }

    // value-halving butterfly over the 16 lo-lanes: lane lo ends with row lo
    const int b0 = lo & 1, b1 = (lo >> 1) & 1, b2 = (lo >> 2) & 1, b3 = (lo >> 3) & 1;
    float v8[8];
    #pragma unroll
    for (int k = 0; k < 8; ++k) {
        float keep = b0 ? v16[2*k+1] : v16[2*k];
        float send = b0 ? v16[2*k]   : v16[2*k+1];
        v8[k] = keep + __shfl_xor(send, 1, 64);
    }
    float v4[4];
    #pragma unroll
    for (int k = 0; k < 4; ++k) {
        float keep = b1 ? v8[2*k+1] : v8[2*k];
        float send = b1 ? v8[2*k]   : v8[2*k+1];
        v4[k] = keep + __shfl_xor(send, 2, 64);
    }
    float v2[2];
    #pragma unroll
    for (int k = 0; k < 2; ++k) {
        float keep = b2 ? v4[2*k+1] : v4[2*k];
        float send = b2 ? v4[2*k]   : v4[2*k+1];
        v2[k] = keep + __shfl_xor(send, 4, 64);
    }
    {
        float keep = b3 ? v2[1] : v2[0];
        float send = b3 ? v2[0] : v2[1];
        float vt = keep + __shfl_xor(send, 8, 64);
        const int n_out = n_base + (lo >> 2) * 16 + g * 4 + (lo & 3);
        psum[(size_t)n_out * CHUNKS + chunk] = vt;
    }
#undef LDA
#undef LDB
#undef MM16
#undef PH3
}

// ---------------- kernel 4: per-row combine + margin fix-up ----------------
__global__ __launch_bounds__(256) void row_reduce(
    const float* __restrict__ psum, const float* __restrict__ tgt,
    float* __restrict__ row_loss, int CHUNKS)
{
    const int n = blockIdx.x;
    const int tid = threadIdx.x;
    __shared__ float sm[256];

    float s = 0.f;
    for (int j = tid; j < CHUNKS; j += 256) s += psum[(size_t)n * CHUNKS + j];
    sm[tid] = s; __syncthreads();
    for (int st = 128; st > 0; st >>= 1) {
        if (tid < st) sm[tid] += sm[tid + st];
        __syncthreads();
    }
    if (tid == 0) {
        const float tl = tgt[n];                       // margined target logit
        // raw sum includes pad cols (96*exp(-30)) and the UNMARGINED target
        // term exp(tl+10.5-30); swap in the margined term exp(tl-30).
        float S = sm[0] - PADC - expf(tl - (AMSM_SCALE - AMSM_SCALE*AMSM_MARGIN))
                + expf(tl - AMSM_SCALE);
        row_loss[n] = (logf(S) + AMSM_SCALE) - tl;
    }
}

// ---------------- kernel 5: mean over rows -> scalar ----------------
__global__ __launch_bounds__(256) void final_reduce(
    const float* __restrict__ row_loss, float* __restrict__ out, int N)
{
    const int tid = threadIdx.x;
    __shared__ float sm[256];
    float s = 0.f;
    for (int i = tid; i < N; i += 256) s += row_loss[i];
    sm[tid] = s; __syncthreads();
    for (int st = 128; st > 0; st >>= 1) {
        if (tid < st) sm[tid] += sm[tid + st];
        __syncthreads();
    }
    if (tid == 0) out[0] = sm[0] / (float)N;
}

// ---------------- launch ----------------
extern "C" void kernel_launch(void* const* d_in, const int* in_sizes, int n_in,
                              void* d_out, int out_size, void* d_ws, size_t ws_size,
                              hipStream_t stream) {
    const float* x  = (const float*)d_in[0];
    const float* W  = (const float*)d_in[1];
    const int*   lb = (const int*)d_in[2];
    float* out = (float*)d_out;

    constexpr int N  = 2048, D = 512, C = 100000;
    constexpr int C_PAD  = CTILES * 256;     // 100096
    constexpr int CHUNKS = CTILES * 4;       // 1564 (one per 64-col wave stripe)

    char* ws = (char*)d_ws;
    auto alloc = [&](size_t bytes) {
        char* p = ws; ws += (bytes + 255) & ~(size_t)255; return p;
    };
    signed char* Wq  = (signed char*)alloc((size_t)C_PAD * D);          // 51.2 MB
    signed char* xqv = (signed char*)alloc((size_t)N * D);              // 1 MB
    float*  sw   = (float*)alloc((size_t)C_PAD * sizeof(float));        // 400 KB
    float*  sx   = (float*)alloc((size_t)N * sizeof(float));
    float*  psum = (float*)alloc((size_t)N * CHUNKS * sizeof(float));   // 12.8 MB
    float*  tgtv = (float*)alloc((size_t)N * sizeof(float));
    float*  rl   = (float*)alloc((size_t)N * sizeof(float));

    rownorm_i8<<<N / 4, 256, 0, stream>>>(x, xqv, sx, N, N);
    rownorm_i8<<<C_PAD / 4, 256, 0, stream>>>(W, Wq, sw, C, C_PAD);
    target_logit<<<N / 4, 256, 0, stream>>>(xqv, Wq, sx, sw, lb, tgtv, N);

    amsm_gemm<<<16 * CTILES, 512, 0, stream>>>(xqv, Wq, sx, sw, psum, CHUNKS);

    row_reduce<<<N, 256, 0, stream>>>(psum, tgtv, rl, CHUNKS);
    final_reduce<<<1, 256, 0, stream>>>(rl, out, N);
}

// Round 12
// 177.673 us; speedup vs baseline: 2.0968x; 1.0608x over previous
//
#include <hip/hip_runtime.h>
#include <hip/hip_bf16.h>
#include <cfloat>
#include <math.h>

// ---------------- types ----------------
typedef int   int32x4 __attribute__((ext_vector_type(4)));

#define AMSM_MARGIN 0.35f
#define AMSM_SCALE  30.0f
#define AMSM_EPS    1e-12f
#define L2E         1.4426950408889634f
#define BEXP        (-AMSM_SCALE * L2E)          // exp(logit-30) = exp2(f*acc + BEXP)
#define PADC        8.9833181e-12f               // 96 * exp(-30): pad-column constant

// ------------- kernel 1/2: row-normalize f32 -> per-row-scaled i8 ---------
__global__ __launch_bounds__(256) void rownorm_i8(
    const float* __restrict__ src, signed char* __restrict__ dst,
    float* __restrict__ scale, int nrows, int nrows_pad)
{
    int row  = blockIdx.x * 4 + (threadIdx.x >> 6);
    int lane = threadIdx.x & 63;
    if (row >= nrows_pad) return;

    signed char* drow = dst + (size_t)row * 512 + lane * 8;

    if (row >= nrows) {           // zero-fill pad rows
        *(int2*)drow = make_int2(0, 0);
        if (lane == 0) scale[row] = 0.f;
        return;
    }
    const float4* p = (const float4*)(src + (size_t)row * 512 + lane * 8);
    float4 a = p[0], b = p[1];
    float ss = a.x*a.x + a.y*a.y + a.z*a.z + a.w*a.w
             + b.x*b.x + b.y*b.y + b.z*b.z + b.w*b.w;
    #pragma unroll
    for (int m = 1; m < 64; m <<= 1) ss += __shfl_xor(ss, m, 64);
    float r = 1.0f / sqrtf(ss + AMSM_EPS);

    float v[8] = { a.x*r, a.y*r, a.z*r, a.w*r, b.x*r, b.y*r, b.z*r, b.w*r };
    float mx = 0.f;
    #pragma unroll
    for (int i = 0; i < 8; ++i) mx = fmaxf(mx, fabsf(v[i]));
    #pragma unroll
    for (int m = 1; m < 64; m <<= 1) mx = fmaxf(mx, __shfl_xor(mx, m, 64));
    float qs = 127.0f / mx;       // mx >= 1/sqrt(512) > 0 for a unit vector

    int q[8];
    #pragma unroll
    for (int i = 0; i < 8; ++i) {
        float t = rintf(v[i] * qs);
        t = fmaxf(-127.f, fminf(127.f, t));
        q[i] = (int)t;
    }
    unsigned int lo32 = (q[0]&255) | ((q[1]&255)<<8) | ((q[2]&255)<<16) | ((unsigned)(q[3]&255)<<24);
    unsigned int hi32 = (q[4]&255) | ((q[5]&255)<<8) | ((q[6]&255)<<16) | ((unsigned)(q[7]&255)<<24);
    *(int2*)drow = make_int2((int)lo32, (int)hi32);
    if (lane == 0) scale[row] = mx * (1.0f / 127.0f);
}

// ------------- kernel 2b: exact target logit (margined) per row -----------
// one wave per row: tl = 30*sa[n]*sb[c]*dot(xq[n],Wq[c]) - 10.5
__global__ __launch_bounds__(256) void target_logit(
    const signed char* __restrict__ xq, const signed char* __restrict__ Wq,
    const float* __restrict__ sa, const float* __restrict__ sb,
    const int* __restrict__ lb, float* __restrict__ tgt, int N)
{
    int n    = blockIdx.x * 4 + (threadIdx.x >> 6);
    int lane = threadIdx.x & 63;
    if (n >= N) return;
    const int c = lb[n];
    int2 a = *(const int2*)(xq + (size_t)n * 512 + lane * 8);
    int2 b = *(const int2*)(Wq + (size_t)c * 512 + lane * 8);
    int d = 0;
    #pragma unroll
    for (int i = 0; i < 4; ++i)
        d += ((a.x << (24 - 8*i)) >> 24) * ((b.x << (24 - 8*i)) >> 24);
    #pragma unroll
    for (int i = 0; i < 4; ++i)
        d += ((a.y << (24 - 8*i)) >> 24) * ((b.y << (24 - 8*i)) >> 24);
    #pragma unroll
    for (int m = 1; m < 64; m <<= 1) d += __shfl_xor(d, m, 64);
    if (lane == 0)
        tgt[n] = AMSM_SCALE * sa[n] * sb[c] * (float)d - AMSM_SCALE * AMSM_MARGIN;
}

// ---------------- kernel 3: 128x256 i8 triple-buffered GEMM + sum-exp -----
// Geometry/schedule identical to r9/r10. ONE change vs r10: the per-logit
// exp uses __builtin_amdgcn_exp2f (single v_exp_f32) instead of the ocml
// exp2f libcall (~12-15 VALU instrs w/ denorm handling) -- r10's VALUBusy=63%
// was dominated by that libcall. Arg range [-200,0] flushes safely.
#define CTILES 391    // 100096 / 256

__device__ __forceinline__ void load_lds16(const void* g, void* l) {
    __builtin_amdgcn_global_load_lds(
        (const __attribute__((address_space(1))) void*)g,
        (__attribute__((address_space(3))) void*)l, 16, 0, 0);
}

#define BAR() __builtin_amdgcn_s_barrier()
#define VMC(N) asm volatile("s_waitcnt vmcnt(" #N ")" ::: "memory")

__global__ __launch_bounds__(512, 4) void amsm_gemm(
    const signed char* __restrict__ xq, const signed char* __restrict__ Wq,
    const float* __restrict__ sa, const float* __restrict__ sb,
    float* __restrict__ psum, int CHUNKS)
{
    __shared__ char lds[73728];   // A: [3][8192] at 0; B: [3][16384] at 24576

    // T1: bijective XCD swizzle (6256 = 8 * 782)
    const int bid = blockIdx.x;
    const int wid = (bid & 7) * 782 + (bid >> 3);
    const int mt  = wid & 15;           // m fast -> same-XCD blocks share W band
    const int ct  = wid >> 4;
    const int m0  = mt * 128;
    const int c0  = ct * 256;

    const int tid  = threadIdx.x;
    const int lane = tid & 63;
    const int w    = tid >> 6;
    const int wr   = w >> 2;            // 0..1 (M)
    const int wc   = w & 3;             // 0..3 (N)
    const int g    = lane >> 4;
    const int lo   = lane & 15;

    const signed char* gA = xq + (size_t)m0 * 512;
    const signed char* gB = Wq + (size_t)c0 * 512;

    auto stageA = [&](int b, int kt) {
        const int q   = tid;                        // 512 x 16B = 128 rows x 64B
        const int row = q >> 2;
        const int kc  = (q & 3) ^ ((q >> 4) & 2);   // T2 involution (source)
        load_lds16(gA + (size_t)row * 512 + kt * 64 + kc * 16,
                   lds + b * 8192 + q * 16);
    };
    auto stageB = [&](int b, int kt) {
        #pragma unroll
        for (int iss = 0; iss < 2; ++iss) {
            const int q   = iss * 512 + tid;        // 1024 x 16B = 256 rows x 64B
            const int row = q >> 2;
            const int kc  = (q & 3) ^ ((q >> 4) & 2);
            load_lds16(gB + (size_t)row * 512 + kt * 64 + kc * 16,
                       lds + 24576 + b * 16384 + q * 16);
        }
    };

    const int kxb  = (g ^ ((lo >> 2) & 2)) * 16;    // T2 involution (read), bytes
    const int aoff = (wr * 64 + lo) * 64 + kxb;     // byte off within A region
    const int boff = (wc * 64 + lo) * 64 + kxb;     // within B region

    int32x4 acc[4][4] = {};
    int32x4 af[4], bfr[4];

#define LDA(B) { const char* rb_ = lds + (B)*8192 + aoff; \
    _Pragma("unroll") for (int mi_ = 0; mi_ < 4; ++mi_) \
        af[mi_] = *(const int32x4*)(rb_ + mi_*1024); }
#define LDB(B) { const char* rb_ = lds + 24576 + (B)*16384 + boff; \
    _Pragma("unroll") for (int ni_ = 0; ni_ < 4; ++ni_) \
        bfr[ni_] = *(const int32x4*)(rb_ + ni_*1024); }
#define MM16() __builtin_amdgcn_s_setprio(1); \
    _Pragma("unroll") for (int mi_ = 0; mi_ < 4; ++mi_) \
      _Pragma("unroll") for (int ni_ = 0; ni_ < 4; ++ni_) \
        acc[mi_][ni_] = __builtin_amdgcn_mfma_i32_16x16x64_i8(af[mi_], bfr[ni_], acc[mi_][ni_], 0,0,0); \
    __builtin_amdgcn_s_setprio(0);
#define PH3(BUF, SBUF, T2)  { LDA(BUF); LDB(BUF); stageA(SBUF, T2); stageB(SBUF, T2); \
    MM16(); VMC(3); BAR(); }

    // ---- prologue: tiles 0,1 -> bufs 0,1 (6 loads; drain tile0's 3) ----
    stageA(0, 0); stageB(0, 0);
    stageA(1, 1); stageB(1, 1);
    VMC(3); BAR();

    // ---- 8 K-steps (BK=64); phase t reads buf t%3, stages t+2 -> (t+2)%3 --
    PH3(0, 2, 2);   // t=0
    PH3(1, 0, 3);   // t=1
    PH3(2, 1, 4);   // t=2
    PH3(0, 2, 5);   // t=3
    PH3(1, 0, 6);   // t=4
    PH3(2, 1, 7);   // t=5
    LDA(0); LDB(0); MM16(); VMC(0); BAR();   // t=6 (drain tile7)
    LDA(1); LDB(1); MM16();                  // t=7

    // ---- epilogue ----
    const int n_base = m0 + wr * 64;
    const int c_base = c0 + wc * 64;
    const int chunk  = ct * 4 + wc;

    float sbv[4];
    #pragma unroll
    for (int ni = 0; ni < 4; ++ni) sbv[ni] = sb[c_base + ni * 16 + lo];

    // v16[r], r = mi*4+j  <->  row n = n_base + (r>>2)*16 + g*4 + (r&3)
    float v16[16];
    #pragma unroll
    for (int mi = 0; mi < 4; ++mi) {
        float4 sa4 = *(const float4*)(sa + n_base + mi * 16 + g * 4);
        const float* sap = (const float*)&sa4;
        #pragma unroll
        for (int j = 0; j < 4; ++j) {
            const float stf = (AMSM_SCALE * L2E) * sap[j];
            float s = 0.f;
            #pragma unroll
            for (int ni = 0; ni < 4; ++ni)
                s += __builtin_amdgcn_exp2f(
                        fmaf((float)acc[mi][ni][j], stf * sbv[ni], BEXP));
            v16[mi * 4 + j] = s;
        }
    }

    // value-halving butterfly over the 16 lo-lanes: lane lo ends with row lo
    const int b0 = lo & 1, b1 = (lo >> 1) & 1, b2 = (lo >> 2) & 1, b3 = (lo >> 3) & 1;
    float v8[8];
    #pragma unroll
    for (int k = 0; k < 8; ++k) {
        float keep = b0 ? v16[2*k+1] : v16[2*k];
        float send = b0 ? v16[2*k]   : v16[2*k+1];
        v8[k] = keep + __shfl_xor(send, 1, 64);
    }
    float v4[4];
    #pragma unroll
    for (int k = 0; k < 4; ++k) {
        float keep = b1 ? v8[2*k+1] : v8[2*k];
        float send = b1 ? v8[2*k]   : v8[2*k+1];
        v4[k] = keep + __shfl_xor(send, 2, 64);
    }
    float v2[2];
    #pragma unroll
    for (int k = 0; k < 2; ++k) {
        float keep = b2 ? v4[2*k+1] : v4[2*k];
        float send = b2 ? v4[2*k]   : v4[2*k+1];
        v2[k] = keep + __shfl_xor(send, 4, 64);
    }
    {
        float keep = b3 ? v2[1] : v2[0];
        float send = b3 ? v2[0] : v2[1];
        float vt = keep + __shfl_xor(send, 8, 64);
        const int n_out = n_base + (lo >> 2) * 16 + g * 4 + (lo & 3);
        psum[(size_t)n_out * CHUNKS + chunk] = vt;
    }
#undef LDA
#undef LDB
#undef MM16
#undef PH3
}

// ---------------- kernel 4: per-row combine + margin fix-up ----------------
__global__ __launch_bounds__(256) void row_reduce(
    const float* __restrict__ psum, const float* __restrict__ tgt,
    float* __restrict__ row_loss, int CHUNKS)
{
    const int n = blockIdx.x;
    const int tid = threadIdx.x;
    __shared__ float sm[256];

    float s = 0.f;
    for (int j = tid; j < CHUNKS; j += 256) s += psum[(size_t)n * CHUNKS + j];
    sm[tid] = s; __syncthreads();
    for (int st = 128; st > 0; st >>= 1) {
        if (tid < st) sm[tid] += sm[tid + st];
        __syncthreads();
    }
    if (tid == 0) {
        const float tl = tgt[n];                       // margined target logit
        // raw sum includes pad cols (96*exp(-30)) and the UNMARGINED target
        // term exp(tl+10.5-30); swap in the margined term exp(tl-30).
        float S = sm[0] - PADC - expf(tl - (AMSM_SCALE - AMSM_SCALE*AMSM_MARGIN))
                + expf(tl - AMSM_SCALE);
        row_loss[n] = (logf(S) + AMSM_SCALE) - tl;
    }
}

// ---------------- kernel 5: mean over rows -> scalar ----------------
__global__ __launch_bounds__(256) void final_reduce(
    const float* __restrict__ row_loss, float* __restrict__ out, int N)
{
    const int tid = threadIdx.x;
    __shared__ float sm[256];
    float s = 0.f;
    for (int i = tid; i < N; i += 256) s += row_loss[i];
    sm[tid] = s; __syncthreads();
    for (int st = 128; st > 0; st >>= 1) {
        if (tid < st) sm[tid] += sm[tid + st];
        __syncthreads();
    }
    if (tid == 0) out[0] = sm[0] / (float)N;
}

// ---------------- launch ----------------
extern "C" void kernel_launch(void* const* d_in, const int* in_sizes, int n_in,
                              void* d_out, int out_size, void* d_ws, size_t ws_size,
                              hipStream_t stream) {
    const float* x  = (const float*)d_in[0];
    const float* W  = (const float*)d_in[1];
    const int*   lb = (const int*)d_in[2];
    float* out = (float*)d_out;

    constexpr int N  = 2048, D = 512, C = 100000;
    constexpr int C_PAD  = CTILES * 256;     // 100096
    constexpr int CHUNKS = CTILES * 4;       // 1564 (one per 64-col wave stripe)

    char* ws = (char*)d_ws;
    auto alloc = [&](size_t bytes) {
        char* p = ws; ws += (bytes + 255) & ~(size_t)255; return p;
    };
    signed char* Wq  = (signed char*)alloc((size_t)C_PAD * D);          // 51.2 MB
    signed char* xqv = (signed char*)alloc((size_t)N * D);              // 1 MB
    float*  sw   = (float*)alloc((size_t)C_PAD * sizeof(float));        // 400 KB
    float*  sx   = (float*)alloc((size_t)N * sizeof(float));
    float*  psum = (float*)alloc((size_t)N * CHUNKS * sizeof(float));   // 12.8 MB
    float*  tgtv = (float*)alloc((size_t)N * sizeof(float));
    float*  rl   = (float*)alloc((size_t)N * sizeof(float));

    rownorm_i8<<<N / 4, 256, 0, stream>>>(x, xqv, sx, N, N);
    rownorm_i8<<<C_PAD / 4, 256, 0, stream>>>(W, Wq, sw, C, C_PAD);
    target_logit<<<N / 4, 256, 0, stream>>>(xqv, Wq, sx, sw, lb, tgtv, N);

    amsm_gemm<<<16 * CTILES, 512, 0, stream>>>(xqv, Wq, sx, sw, psum, CHUNKS);

    row_reduce<<<N, 256, 0, stream>>>(psum, tgtv, rl, CHUNKS);
    final_reduce<<<1, 256, 0, stream>>>(rl, out, N);
}